// Round 15
// baseline (836.199 us; speedup 1.0000x reference)
//
#include <hip/hip_runtime.h>
#include <hip/hip_bf16.h>
#include <stdint.h>

#define NN 50000
#define EE 800000
#define GG 64
#define NOTESD 128
#define MPAD 50048
#define TM_TILES 391
#define NCHUNK 98
#define LDSW 40
#define CHS 1288   // AC chunk stride in elements: 32*40 + 8 pad (word stride 644 % 32 == 4)

typedef unsigned short u16;
typedef __attribute__((ext_vector_type(8))) short short8;
typedef __attribute__((ext_vector_type(4))) float f32x4;

__device__ __forceinline__ float b2f(u16 u) {
  union { uint32_t i; float f; } x; x.i = ((uint32_t)u) << 16; return x.f;
}
__device__ __forceinline__ u16 f2b(float f) {
  __hip_bfloat16 h = __float2bfloat16(f);
  return *reinterpret_cast<u16*>(&h);
}

// ---------------- CSR build ----------------
__global__ void k_hist(const int* __restrict__ dst, int* __restrict__ cnt) {
  int e = blockIdx.x * 256 + threadIdx.x;
  if (e < EE) atomicAdd(&cnt[dst[e]], 1);
}

__global__ void k_scan1(const int* __restrict__ cnt, int* __restrict__ indptr,
                        int* __restrict__ csum) {
  __shared__ int s[512];
  int t = threadIdx.x;
  int i = blockIdx.x * 512 + t;
  int v = (i < NN) ? cnt[i] : 0;
  s[t] = v; __syncthreads();
  for (int d = 1; d < 512; d <<= 1) {
    int x = (t >= d) ? s[t - d] : 0;
    __syncthreads();
    s[t] += x;
    __syncthreads();
  }
  if (i < NN) indptr[i] = s[t] - v;
  if (t == 511) csum[blockIdx.x] = s[t];
}

// scan2 merged: each block reduces csum[0..blockIdx) itself
__global__ void k_scan3b(const int* __restrict__ csum, int* __restrict__ indptr,
                         int* __restrict__ cursor) {
  __shared__ int sarr[128];
  int t = threadIdx.x;
  if (t < 128) sarr[t] = (t < blockIdx.x) ? csum[t] : 0;
  __syncthreads();
  for (int d = 64; d > 0; d >>= 1) {
    if (t < d) sarr[t] += sarr[t + d];
    __syncthreads();
  }
  int off = sarr[0];
  int i = blockIdx.x * 512 + t;
  if (i < NN) {
    int v = indptr[i] + off;
    indptr[i] = v;
    cursor[i] = v;
  }
}

__global__ void k_fill(const int* __restrict__ src, const int* __restrict__ dst,
                       int* __restrict__ cursor, int* __restrict__ csr) {
  int e = blockIdx.x * 256 + threadIdx.x;
  if (e < EE) {
    int p = atomicAdd(&cursor[dst[e]], 1);
    csr[p] = src[e];
  }
}

// ---------------- all 9 weight transposes (fp32 -> bf16, 256x256 each) ----------------
__global__ void k_transpose_all(const float* __restrict__ proj, const float* __restrict__ W1,
                                const float* __restrict__ W2, u16* __restrict__ WT) {
  __shared__ float tile[32][33];
  int mat = blockIdx.x >> 6;
  int bid = blockIdx.x & 63;
  const float* W = (mat == 0) ? proj
                 : (mat <= 4) ? W1 + (size_t)(mat - 1) * 65536
                              : W2 + (size_t)(mat - 5) * 65536;
  u16* dst = WT + (size_t)mat * 65536;
  int bx = bid & 7, by = bid >> 3;
  int tx = threadIdx.x & 31, ty = threadIdx.x >> 5;
#pragma unroll
  for (int i = 0; i < 32; i += 8)
    tile[ty + i][tx] = W[(by * 32 + ty + i) * 256 + bx * 32 + tx];
  __syncthreads();
#pragma unroll
  for (int i = 0; i < 32; i += 8)
    dst[(bx * 32 + ty + i) * 256 + by * 32 + tx] = f2b(tile[tx][ty + i]);
}

// ---------------- one-pass column stats for fp32 x ----------------
__global__ void k_colstats_f32(const float* __restrict__ X, float* __restrict__ sum,
                               float* __restrict__ sq) {
  int t = threadIdx.x;
  float s = 0.f, q = 0.f;
  for (int r = blockIdx.x; r < NN; r += gridDim.x) {
    float v = X[(size_t)r * 256 + t];
    s += v; q += v * v;
  }
  atomicAdd(&sum[t], s);
  atomicAdd(&sq[t], q);
}

// ---------------- BN apply to fp32 x -> bf16 xn ----------------
__global__ void k_bnx(const float* __restrict__ X, const float* __restrict__ sum,
                      const float* __restrict__ sq, const float* __restrict__ g,
                      const float* __restrict__ b, u16* __restrict__ Y) {
  int t = threadIdx.x;
  float mu = sum[t] * (1.0f / NN);
  float var = fmaxf(sq[t] * (1.0f / NN) - mu * mu, 0.f);
  float rs = rsqrtf(var + 1e-5f);
  float ga = g[t] * rs;
  float be = b[t] - mu * ga;
  for (int r = blockIdx.x; r < NN; r += gridDim.x) {
    float v = X[(size_t)r * 256 + t];
    Y[(size_t)r * 256 + t] = f2b(v * ga + be);
  }
}

// ---------------- BN + relu + residual: h = relu(bn(m2)) + h ----------------
__global__ void k_bnres(const u16* __restrict__ M2, const float* __restrict__ sum,
                        const float* __restrict__ sq, const float* __restrict__ g,
                        const float* __restrict__ b, u16* __restrict__ h) {
  int t = threadIdx.x;
  float mu = sum[t] * (1.0f / NN);
  float var = fmaxf(sq[t] * (1.0f / NN) - mu * mu, 0.f);
  float rs = rsqrtf(var + 1e-5f);
  float ga = g[t] * rs;
  float be = b[t] - mu * ga;
  for (int r = blockIdx.x; r < NN; r += gridDim.x) {
    float v = b2f(M2[(size_t)r * 256 + t]) * ga + be;
    v = fmaxf(v, 0.f);
    float hp = b2f(h[(size_t)r * 256 + t]);
    h[(size_t)r * 256 + t] = f2b(v + hp);
  }
}

// ---------------- last layer: BN + relu + residual fused with mean-pool ----------------
__global__ void k_bnres_pool(const u16* __restrict__ M2, const float* __restrict__ sum,
                             const float* __restrict__ sq, const float* __restrict__ g,
                             const float* __restrict__ b, const u16* __restrict__ h,
                             const int* __restrict__ batch, float* __restrict__ pooled,
                             int* __restrict__ gcnt) {
  __shared__ int bg[128];
  int t = threadIdx.x;
  int r0 = blockIdx.x * 128;
  int rend = min(r0 + 128, NN);
  if (r0 >= NN) return;
  if (t < 128 && r0 + t < NN) bg[t] = batch[r0 + t];
  __syncthreads();
  float mu = sum[t] * (1.0f / NN);
  float var = fmaxf(sq[t] * (1.0f / NN) - mu * mu, 0.f);
  float rs = rsqrtf(var + 1e-5f);
  float ga = g[t] * rs;
  float be = b[t] - mu * ga;
  float a = 0.f;
  int cur = bg[0];
  int cl = 0;
  for (int r = r0; r < rend; ++r) {
    int gg = bg[r - r0];
    if (gg != cur) {
      atomicAdd(&pooled[(size_t)cur * 256 + t], a);
      if (t == 0) atomicAdd(&gcnt[cur], cl);
      a = 0.f; cl = 0; cur = gg;
    }
    float v = b2f(M2[(size_t)r * 256 + t]) * ga + be;
    v = fmaxf(v, 0.f);
    a += v + b2f(h[(size_t)r * 256 + t]);
    cl++;
  }
  atomicAdd(&pooled[(size_t)cur * 256 + t], a);
  if (t == 0) atomicAdd(&gcnt[cur], cl);
}

// ---------------- GEMM (proj only): C = relu(A @ W + bias) ----------------
__global__ __launch_bounds__(256) void k_gemm(const u16* __restrict__ A,
                                              const u16* __restrict__ BT,
                                              const float* __restrict__ bias,
                                              u16* __restrict__ C, int relu) {
  __shared__ __align__(16) u16 As[128 * LDSW];
  __shared__ __align__(16) u16 Bs[128 * LDSW];
  int tid = threadIdx.x;
  int bid = blockIdx.x;
  int tn = bid & 1, tm = bid >> 1;
  int w = tid >> 6, l = tid & 63;
  int wr = (w >> 1) * 64, wc = (w & 1) * 64;

  const u16* Ag = A + (size_t)tm * 128 * 256;
  const u16* Bg = BT + (size_t)tn * 128 * 256;

  f32x4 zz; zz[0] = 0.f; zz[1] = 0.f; zz[2] = 0.f; zz[3] = 0.f;
  f32x4 acc[4][4];
#pragma unroll
  for (int m = 0; m < 4; ++m)
#pragma unroll
    for (int n = 0; n < 4; ++n) acc[m][n] = zz;

  int r0 = w * 16 + (l >> 2);
  int r1 = r0 + 64;
  int kc = (l & 3) * 8;
  int w0 = r0 * LDSW + (l & 3) * 8;
  int w1 = r1 * LDSW + (l & 3) * 8;

  short8 pa0 = *(const short8*)(Ag + (size_t)r0 * 256 + kc);
  short8 pa1 = *(const short8*)(Ag + (size_t)r1 * 256 + kc);
  short8 pb0 = *(const short8*)(Bg + (size_t)r0 * 256 + kc);
  short8 pb1 = *(const short8*)(Bg + (size_t)r1 * 256 + kc);

  for (int kk = 0; kk < 8; ++kk) {
    *(short8*)&As[w0] = pa0;
    *(short8*)&As[w1] = pa1;
    *(short8*)&Bs[w0] = pb0;
    *(short8*)&Bs[w1] = pb1;
    if (kk < 7) {
      int k0 = (kk + 1) * 32 + kc;
      pa0 = *(const short8*)(Ag + (size_t)r0 * 256 + k0);
      pa1 = *(const short8*)(Ag + (size_t)r1 * 256 + k0);
      pb0 = *(const short8*)(Bg + (size_t)r0 * 256 + k0);
      pb1 = *(const short8*)(Bg + (size_t)r1 * 256 + k0);
    }
    __syncthreads();
    short8 af[4], bfr[4];
#pragma unroll
    for (int m = 0; m < 4; ++m) {
      int row = wr + m * 16 + (l & 15);
      af[m] = *(const short8*)&As[row * LDSW + (l >> 4) * 8];
    }
#pragma unroll
    for (int n = 0; n < 4; ++n) {
      int row = wc + n * 16 + (l & 15);
      bfr[n] = *(const short8*)&Bs[row * LDSW + (l >> 4) * 8];
    }
#pragma unroll
    for (int m = 0; m < 4; ++m)
#pragma unroll
      for (int n = 0; n < 4; ++n)
        acc[m][n] = __builtin_amdgcn_mfma_f32_16x16x32_bf16(af[m], bfr[n], acc[m][n], 0, 0, 0);
    __syncthreads();
  }

  int colb = tn * 128 + wc;
  int rowb = tm * 128 + wr + (l >> 4) * 4;
#pragma unroll
  for (int n = 0; n < 4; ++n) {
    int c = colb + n * 16 + (l & 15);
    float bz = bias[c];
#pragma unroll
    for (int m = 0; m < 4; ++m) {
      int r = rowb + m * 16;
#pragma unroll
      for (int i = 0; i < 4; ++i) {
        float v = acc[m][n][i] + bz;
        if (relu) v = fmaxf(v, 0.f);
        C[(size_t)(r + i) * 256 + c] = f2b(v);
      }
    }
  }
}

// ---------------- fused agg + GIN MLP ----------------
// Block = 32 nodes. Agg gathers neighbor rows straight into LDS AC (bf16, chunk-major,
// padded chunk stride CHS), then C = relu(A@W1+b1)@W2+b2 with fused stats.
__global__ __launch_bounds__(256) void k_aggmlp(const u16* __restrict__ h,
                                                const int* __restrict__ indptr,
                                                const int* __restrict__ cnt,
                                                const int* __restrict__ csr,
                                                const u16* __restrict__ B1T,
                                                const u16* __restrict__ B2T,
                                                const float* __restrict__ b1,
                                                const float* __restrict__ b2,
                                                u16* __restrict__ C,
                                                float* __restrict__ csum,
                                                float* __restrict__ csq) {
  __shared__ __align__(16) u16 AC[8 * CHS];      // 20608 B: A-tile then C1
  __shared__ __align__(16) u16 Bs[256 * LDSW];   // 20480 B: one k-chunk of W
  int tid = threadIdx.x;
  int tm = blockIdx.x;
  int w = tid >> 6, l = tid & 63;
  int wc = w * 64;
  int sr = tid >> 2;            // Bs staging row group
  int skc = (tid & 3) * 8;      // k offset within chunk

  // B1 chunk-0 prefetch (stays in flight during agg)
  short8 pb[4];
#pragma unroll
  for (int j = 0; j < 4; ++j)
    pb[j] = *(const short8*)(B1T + (size_t)(sr + 64 * j) * 256 + skc);

  // ---- agg phase: node (tm*32 + r), wave w handles r = w*8..w*8+7 ----
  {
    const ushort4* hv = (const ushort4*)h + l;   // lane l: cols 4l..4l+3
    int chunk = l >> 3;
    int cbase = (l * 4) & 31;
    for (int j = 0; j < 8; ++j) {
      int r = w * 8 + j;
      int node = tm * 32 + r;
      float a0 = 0.f, a1 = 0.f, a2 = 0.f, a3 = 0.f;
      if (node < NN) {
        int beg = indptr[node], deg = cnt[node];
        ushort4 v = hv[(size_t)node * 64];
        a0 = b2f(v.x); a1 = b2f(v.y); a2 = b2f(v.z); a3 = b2f(v.w);
        int i = 0;
        for (; i + 8 <= deg; i += 8) {
          int s0 = csr[beg + i + 0], s1 = csr[beg + i + 1];
          int s2 = csr[beg + i + 2], s3 = csr[beg + i + 3];
          int s4 = csr[beg + i + 4], s5 = csr[beg + i + 5];
          int s6 = csr[beg + i + 6], s7 = csr[beg + i + 7];
          ushort4 u0 = hv[(size_t)s0 * 64], u1 = hv[(size_t)s1 * 64];
          ushort4 u2 = hv[(size_t)s2 * 64], u3 = hv[(size_t)s3 * 64];
          ushort4 u4 = hv[(size_t)s4 * 64], u5 = hv[(size_t)s5 * 64];
          ushort4 u6 = hv[(size_t)s6 * 64], u7 = hv[(size_t)s7 * 64];
          a0 += b2f(u0.x) + b2f(u1.x) + b2f(u2.x) + b2f(u3.x)
              + b2f(u4.x) + b2f(u5.x) + b2f(u6.x) + b2f(u7.x);
          a1 += b2f(u0.y) + b2f(u1.y) + b2f(u2.y) + b2f(u3.y)
              + b2f(u4.y) + b2f(u5.y) + b2f(u6.y) + b2f(u7.y);
          a2 += b2f(u0.z) + b2f(u1.z) + b2f(u2.z) + b2f(u3.z)
              + b2f(u4.z) + b2f(u5.z) + b2f(u6.z) + b2f(u7.z);
          a3 += b2f(u0.w) + b2f(u1.w) + b2f(u2.w) + b2f(u3.w)
              + b2f(u4.w) + b2f(u5.w) + b2f(u6.w) + b2f(u7.w);
        }
        for (; i + 4 <= deg; i += 4) {
          int s0 = csr[beg + i + 0], s1 = csr[beg + i + 1];
          int s2 = csr[beg + i + 2], s3 = csr[beg + i + 3];
          ushort4 u0 = hv[(size_t)s0 * 64], u1 = hv[(size_t)s1 * 64];
          ushort4 u2 = hv[(size_t)s2 * 64], u3 = hv[(size_t)s3 * 64];
          a0 += b2f(u0.x) + b2f(u1.x) + b2f(u2.x) + b2f(u3.x);
          a1 += b2f(u0.y) + b2f(u1.y) + b2f(u2.y) + b2f(u3.y);
          a2 += b2f(u0.z) + b2f(u1.z) + b2f(u2.z) + b2f(u3.z);
          a3 += b2f(u0.w) + b2f(u1.w) + b2f(u2.w) + b2f(u3.w);
        }
        for (; i < deg; ++i) {
          int s = csr[beg + i];
          ushort4 u = hv[(size_t)s * 64];
          a0 += b2f(u.x); a1 += b2f(u.y); a2 += b2f(u.z); a3 += b2f(u.w);
        }
      }
      ushort4 o;
      o.x = f2b(a0); o.y = f2b(a1); o.z = f2b(a2); o.w = f2b(a3);
      *(ushort4*)&AC[chunk * CHS + r * LDSW + cbase] = o;
    }
  }

  f32x4 zz; zz[0] = 0.f; zz[1] = 0.f; zz[2] = 0.f; zz[3] = 0.f;
  f32x4 acc[2][4];
#pragma unroll
  for (int m = 0; m < 2; ++m)
#pragma unroll
    for (int n = 0; n < 4; ++n) acc[m][n] = zz;

  // ---- phase 1: acc = A @ W1 ----
  for (int kk = 0; kk < 8; ++kk) {
#pragma unroll
    for (int j = 0; j < 4; ++j)
      *(short8*)&Bs[(sr + 64 * j) * LDSW + skc] = pb[j];
    if (kk < 7) {
      int k0 = (kk + 1) * 32 + skc;
#pragma unroll
      for (int j = 0; j < 4; ++j)
        pb[j] = *(const short8*)(B1T + (size_t)(sr + 64 * j) * 256 + k0);
    }
    __syncthreads();   // covers agg AC writes (kk=0) and Bs chunk
    short8 af[2], bfr[4];
#pragma unroll
    for (int m = 0; m < 2; ++m)
      af[m] = *(const short8*)&AC[kk * CHS + (m * 16 + (l & 15)) * LDSW + (l >> 4) * 8];
#pragma unroll
    for (int n = 0; n < 4; ++n)
      bfr[n] = *(const short8*)&Bs[(wc + n * 16 + (l & 15)) * LDSW + (l >> 4) * 8];
#pragma unroll
    for (int m = 0; m < 2; ++m)
#pragma unroll
      for (int n = 0; n < 4; ++n)
        acc[m][n] = __builtin_amdgcn_mfma_f32_16x16x32_bf16(af[m], bfr[n], acc[m][n], 0, 0, 0);
    __syncthreads();   // all AC/Bs reads of chunk kk complete
  }

  // prefetch W2 chunk 0 (hide under epilogue 1)
  short8 qb[4];
#pragma unroll
  for (int j = 0; j < 4; ++j)
    qb[j] = *(const short8*)(B2T + (size_t)(sr + 64 * j) * 256 + skc);

  // epilogue 1: overwrite AC with C1 = relu(acc + b1)  (AC reads drained by kk=7 barrier)
  {
    int rbase = (l >> 4) * 4;
#pragma unroll
    for (int n = 0; n < 4; ++n) {
      int c = wc + n * 16 + (l & 15);
      float bz = b1[c];
      u16* c1p = &AC[(c >> 5) * CHS + (c & 31)];
#pragma unroll
      for (int m = 0; m < 2; ++m) {
#pragma unroll
        for (int i = 0; i < 4; ++i) {
          float v = fmaxf(acc[m][n][i] + bz, 0.f);
          c1p[(m * 16 + rbase + i) * LDSW] = f2b(v);
        }
        acc[m][n] = zz;  // re-zero for phase 2
      }
    }
  }

  // ---- phase 2: acc = C1 @ W2 ----
  for (int kk = 0; kk < 8; ++kk) {
#pragma unroll
    for (int j = 0; j < 4; ++j)
      *(short8*)&Bs[(sr + 64 * j) * LDSW + skc] = qb[j];
    if (kk < 7) {
      int k0 = (kk + 1) * 32 + skc;
#pragma unroll
      for (int j = 0; j < 4; ++j)
        qb[j] = *(const short8*)(B2T + (size_t)(sr + 64 * j) * 256 + k0);
    }
    __syncthreads();   // C1 writes + Bs chunk visible
    short8 af[2], bfr[4];
#pragma unroll
    for (int m = 0; m < 2; ++m)
      af[m] = *(const short8*)&AC[kk * CHS + (m * 16 + (l & 15)) * LDSW + (l >> 4) * 8];
#pragma unroll
    for (int n = 0; n < 4; ++n)
      bfr[n] = *(const short8*)&Bs[(wc + n * 16 + (l & 15)) * LDSW + (l >> 4) * 8];
#pragma unroll
    for (int m = 0; m < 2; ++m)
#pragma unroll
      for (int n = 0; n < 4; ++n)
        acc[m][n] = __builtin_amdgcn_mfma_f32_16x16x32_bf16(af[m], bfr[n], acc[m][n], 0, 0, 0);
    __syncthreads();
  }

  // epilogue 2 -> global + fused stats
  int rowb = tm * 32 + (l >> 4) * 4;
#pragma unroll
  for (int n = 0; n < 4; ++n) {
    int c = wc + n * 16 + (l & 15);
    float bz = b2[c];
    float s = 0.f, q = 0.f;
#pragma unroll
    for (int m = 0; m < 2; ++m) {
      int r = rowb + m * 16;
#pragma unroll
      for (int i = 0; i < 4; ++i) {
        float v = acc[m][n][i] + bz;
        C[(size_t)(r + i) * 256 + c] = f2b(v);
        if ((r + i) < NN) { s += v; q += v * v; }
      }
    }
    s += __shfl_xor(s, 16); s += __shfl_xor(s, 32);
    q += __shfl_xor(q, 16); q += __shfl_xor(q, 32);
    if ((l >> 4) == 0) {
      atomicAdd(&csum[c], s);
      atomicAdd(&csq[c], q);
    }
  }
}

// ---------------- head: embed + logits (fp32 out) ----------------
__global__ void k_head(const float* __restrict__ pooled, const int* __restrict__ gcnt,
                       const float* __restrict__ predW, const float* __restrict__ predb,
                       float* __restrict__ out) {
  __shared__ float pm[256];
  int g = blockIdx.x, t = threadIdx.x;
  float c = fmaxf((float)gcnt[g], 1.0f);
  float v = pooled[(size_t)g * 256 + t] / c;
  pm[t] = v;
  out[(size_t)g * 256 + t] = v;
  __syncthreads();
  if (t < NOTESD) {
    float acc = predb[t];
    for (int k = 0; k < 256; ++k)
      acc += pm[k] * predW[k * NOTESD + t];
    out[(size_t)GG * 256 + (size_t)g * NOTESD + t] = acc;
  }
}

extern "C" void kernel_launch(void* const* d_in, const int* in_sizes, int n_in,
                              void* d_out, int out_size, void* d_ws, size_t ws_size,
                              hipStream_t stream) {
  const float* x     = (const float*)d_in[0];
  const int*   ei    = (const int*)d_in[1];
  const int*   batch = (const int*)d_in[2];
  const float* fng   = (const float*)d_in[3];
  const float* fnb   = (const float*)d_in[4];
  const float* projW = (const float*)d_in[5];
  const float* projb = (const float*)d_in[6];
  const float* W1    = (const float*)d_in[7];
  const float* b1    = (const float*)d_in[8];
  const float* W2    = (const float*)d_in[9];
  const float* b2    = (const float*)d_in[10];
  const float* bng   = (const float*)d_in[11];
  const float* bnb   = (const float*)d_in[12];
  const float* predW = (const float*)d_in[13];
  const float* predb = (const float*)d_in[14];
  float* out = (float*)d_out;

  char* ws = (char*)d_ws;
  size_t off = 0;
  auto alloc = [&](size_t b) { size_t o = off; off += (b + 255) & ~(size_t)255; return o; };
  u16* h    = (u16*)(ws + alloc((size_t)MPAD * 256 * 2));
  u16* bufA = (u16*)(ws + alloc((size_t)MPAD * 256 * 2));
  u16* bufB = (u16*)(ws + alloc((size_t)MPAD * 256 * 2));
  u16* wt   = (u16*)(ws + alloc((size_t)9 * 65536 * 2));
  size_t statbytes = (size_t)(2560 + GG * 256) * 4 + GG * 4;
  float* statz = (float*)(ws + alloc(statbytes));
  int* cnt     = (int*)(ws + alloc((size_t)NN * 4));
  int* indptr  = (int*)(ws + alloc((size_t)NN * 4));
  int* cursor  = (int*)(ws + alloc((size_t)NN * 4));
  int* csum    = (int*)(ws + alloc(512));
  int* csr     = (int*)(ws + alloc((size_t)EE * 4));
  float* xsum = statz;
  float* xsq  = statz + 256;
  float* pooled = statz + 2560;
  int* gcnt = (int*)(statz + 2560 + GG * 256);

  const int* srcI = ei;
  const int* dstI = ei + EE;

  // zero stats+pooled+gcnt+cnt in one shot; zero bufA pad rows (proj input)
  hipMemsetAsync(statz, 0, statbytes + (size_t)NN * 4, stream);
  hipMemsetAsync(bufA + (size_t)NN * 256, 0, (size_t)(MPAD - NN) * 256 * 2, stream);

  // CSR build
  k_hist<<<(EE + 255) / 256, 256, 0, stream>>>(dstI, cnt);
  k_scan1<<<NCHUNK, 512, 0, stream>>>(cnt, indptr, csum);
  k_scan3b<<<NCHUNK, 512, 0, stream>>>(csum, indptr, cursor);
  k_fill<<<(EE + 255) / 256, 256, 0, stream>>>(srcI, dstI, cursor, csr);

  // all weight transposes in one launch
  k_transpose_all<<<576, 256, 0, stream>>>(projW, W1, W2, wt);

  // feature BN -> bufA
  k_colstats_f32<<<512, 256, 0, stream>>>(x, xsum, xsq);
  k_bnx<<<512, 256, 0, stream>>>(x, xsum, xsq, fng, fnb, bufA);

  // projection: h = relu(xn @ projW + projb)
  k_gemm<<<TM_TILES * 2, 256, 0, stream>>>(bufA, wt, projb, h, 1);

  for (int l = 0; l < 4; ++l) {
    float* lsum = statz + 512 + l * 512;
    float* lsq  = lsum + 256;
    k_aggmlp<<<MPAD / 32, 256, 0, stream>>>(h, indptr, cnt, csr,
                                            wt + (size_t)(1 + l) * 65536,
                                            wt + (size_t)(5 + l) * 65536,
                                            b1 + (size_t)l * 256, b2 + (size_t)l * 256,
                                            bufB, lsum, lsq);
    if (l < 3) {
      k_bnres<<<512, 256, 0, stream>>>(bufB, lsum, lsq, bng + (size_t)l * 256,
                                       bnb + (size_t)l * 256, h);
    } else {
      k_bnres_pool<<<(NN + 127) / 128, 256, 0, stream>>>(bufB, lsum, lsq,
                                                         bng + (size_t)l * 256,
                                                         bnb + (size_t)l * 256, h,
                                                         batch, pooled, gcnt);
    }
  }

  // readout
  k_head<<<GG, 256, 0, stream>>>(pooled, gcnt, predW, predb, out);
}

// Round 18
// 725.645 us; speedup vs baseline: 1.1524x; 1.1524x over previous
//
#include <hip/hip_runtime.h>
#include <hip/hip_bf16.h>
#include <stdint.h>

#define NN 50000
#define EE 800000
#define GG 64
#define NOTESD 128
#define MPAD 50048
#define TM_TILES 391
#define NCHUNK 98
#define LDSW 40

typedef unsigned short u16;
typedef __attribute__((ext_vector_type(8))) short short8;
typedef __attribute__((ext_vector_type(4))) float f32x4;

__device__ __forceinline__ float b2f(u16 u) {
  union { uint32_t i; float f; } x; x.i = ((uint32_t)u) << 16; return x.f;
}
__device__ __forceinline__ u16 f2b(float f) {
  __hip_bfloat16 h = __float2bfloat16(f);
  return *reinterpret_cast<u16*>(&h);
}

// ---------------- CSR build ----------------
__global__ void k_hist(const int* __restrict__ dst, int* __restrict__ cnt) {
  int e = blockIdx.x * 256 + threadIdx.x;
  if (e < EE) atomicAdd(&cnt[dst[e]], 1);
}

__global__ void k_scan1(const int* __restrict__ cnt, int* __restrict__ indptr,
                        int* __restrict__ csum) {
  __shared__ int s[512];
  int t = threadIdx.x;
  int i = blockIdx.x * 512 + t;
  int v = (i < NN) ? cnt[i] : 0;
  s[t] = v; __syncthreads();
  for (int d = 1; d < 512; d <<= 1) {
    int x = (t >= d) ? s[t - d] : 0;
    __syncthreads();
    s[t] += x;
    __syncthreads();
  }
  if (i < NN) indptr[i] = s[t] - v;
  if (t == 511) csum[blockIdx.x] = s[t];
}

// scan2 merged: each block reduces csum[0..blockIdx) itself
__global__ void k_scan3b(const int* __restrict__ csum, int* __restrict__ indptr,
                         int* __restrict__ cursor) {
  __shared__ int sarr[128];
  int t = threadIdx.x;
  if (t < 128) sarr[t] = (t < blockIdx.x) ? csum[t] : 0;
  __syncthreads();
  for (int d = 64; d > 0; d >>= 1) {
    if (t < d) sarr[t] += sarr[t + d];
    __syncthreads();
  }
  int off = sarr[0];
  int i = blockIdx.x * 512 + t;
  if (i < NN) {
    int v = indptr[i] + off;
    indptr[i] = v;
    cursor[i] = v;
  }
}

__global__ void k_fill(const int* __restrict__ src, const int* __restrict__ dst,
                       int* __restrict__ cursor, int* __restrict__ csr) {
  int e = blockIdx.x * 256 + threadIdx.x;
  if (e < EE) {
    int p = atomicAdd(&cursor[dst[e]], 1);
    csr[p] = src[e];
  }
}

// ---------------- all 9 weight transposes (fp32 -> bf16, 256x256 each) ----------------
__global__ void k_transpose_all(const float* __restrict__ proj, const float* __restrict__ W1,
                                const float* __restrict__ W2, u16* __restrict__ WT) {
  __shared__ float tile[32][33];
  int mat = blockIdx.x >> 6;
  int bid = blockIdx.x & 63;
  const float* W = (mat == 0) ? proj
                 : (mat <= 4) ? W1 + (size_t)(mat - 1) * 65536
                              : W2 + (size_t)(mat - 5) * 65536;
  u16* dst = WT + (size_t)mat * 65536;
  int bx = bid & 7, by = bid >> 3;
  int tx = threadIdx.x & 31, ty = threadIdx.x >> 5;
#pragma unroll
  for (int i = 0; i < 32; i += 8)
    tile[ty + i][tx] = W[(by * 32 + ty + i) * 256 + bx * 32 + tx];
  __syncthreads();
#pragma unroll
  for (int i = 0; i < 32; i += 8)
    dst[(bx * 32 + ty + i) * 256 + by * 32 + tx] = f2b(tile[tx][ty + i]);
}

// ---------------- one-pass column stats for fp32 x ----------------
__global__ void k_colstats_f32(const float* __restrict__ X, float* __restrict__ sum,
                               float* __restrict__ sq) {
  int t = threadIdx.x;
  float s = 0.f, q = 0.f;
  for (int r = blockIdx.x; r < NN; r += gridDim.x) {
    float v = X[(size_t)r * 256 + t];
    s += v; q += v * v;
  }
  atomicAdd(&sum[t], s);
  atomicAdd(&sq[t], q);
}

// ---------------- BN apply to fp32 x -> bf16 xn ----------------
__global__ void k_bnx(const float* __restrict__ X, const float* __restrict__ sum,
                      const float* __restrict__ sq, const float* __restrict__ g,
                      const float* __restrict__ b, u16* __restrict__ Y) {
  int t = threadIdx.x;
  float mu = sum[t] * (1.0f / NN);
  float var = fmaxf(sq[t] * (1.0f / NN) - mu * mu, 0.f);
  float rs = rsqrtf(var + 1e-5f);
  float ga = g[t] * rs;
  float be = b[t] - mu * ga;
  for (int r = blockIdx.x; r < NN; r += gridDim.x) {
    float v = X[(size_t)r * 256 + t];
    Y[(size_t)r * 256 + t] = f2b(v * ga + be);
  }
}

// ---------------- BN + relu + residual: h = relu(bn(m2)) + h ----------------
__global__ void k_bnres(const u16* __restrict__ M2, const float* __restrict__ sum,
                        const float* __restrict__ sq, const float* __restrict__ g,
                        const float* __restrict__ b, u16* __restrict__ h) {
  int t = threadIdx.x;
  float mu = sum[t] * (1.0f / NN);
  float var = fmaxf(sq[t] * (1.0f / NN) - mu * mu, 0.f);
  float rs = rsqrtf(var + 1e-5f);
  float ga = g[t] * rs;
  float be = b[t] - mu * ga;
  for (int r = blockIdx.x; r < NN; r += gridDim.x) {
    float v = b2f(M2[(size_t)r * 256 + t]) * ga + be;
    v = fmaxf(v, 0.f);
    float hp = b2f(h[(size_t)r * 256 + t]);
    h[(size_t)r * 256 + t] = f2b(v + hp);
  }
}

// ---------------- last layer: BN + relu + residual fused with mean-pool ----------------
__global__ void k_bnres_pool(const u16* __restrict__ M2, const float* __restrict__ sum,
                             const float* __restrict__ sq, const float* __restrict__ g,
                             const float* __restrict__ b, const u16* __restrict__ h,
                             const int* __restrict__ batch, float* __restrict__ pooled,
                             int* __restrict__ gcnt) {
  __shared__ int bg[128];
  int t = threadIdx.x;
  int r0 = blockIdx.x * 128;
  int rend = min(r0 + 128, NN);
  if (r0 >= NN) return;
  if (t < 128 && r0 + t < NN) bg[t] = batch[r0 + t];
  __syncthreads();
  float mu = sum[t] * (1.0f / NN);
  float var = fmaxf(sq[t] * (1.0f / NN) - mu * mu, 0.f);
  float rs = rsqrtf(var + 1e-5f);
  float ga = g[t] * rs;
  float be = b[t] - mu * ga;
  float a = 0.f;
  int cur = bg[0];
  int cl = 0;
  for (int r = r0; r < rend; ++r) {
    int gg = bg[r - r0];
    if (gg != cur) {
      atomicAdd(&pooled[(size_t)cur * 256 + t], a);
      if (t == 0) atomicAdd(&gcnt[cur], cl);
      a = 0.f; cl = 0; cur = gg;
    }
    float v = b2f(M2[(size_t)r * 256 + t]) * ga + be;
    v = fmaxf(v, 0.f);
    a += v + b2f(h[(size_t)r * 256 + t]);
    cl++;
  }
  atomicAdd(&pooled[(size_t)cur * 256 + t], a);
  if (t == 0) atomicAdd(&gcnt[cur], cl);
}

// ---------------- aggregation: 8/4/1 ladder + index prefetch pipeline ----------------
__global__ void k_agg(const u16* __restrict__ h, const int* __restrict__ indptr,
                      const int* __restrict__ cnt, const int* __restrict__ csr,
                      u16* __restrict__ out) {
  int w = threadIdx.x >> 6, l = threadIdx.x & 63;
  int node = blockIdx.x * 4 + w;
  if (node >= NN) return;
  int beg = indptr[node], deg = cnt[node];
  const ushort4* hv = (const ushort4*)h + l;
  ushort4 v = hv[(size_t)node * 64];
  float a0 = b2f(v.x), a1 = b2f(v.y), a2 = b2f(v.z), a3 = b2f(v.w);
  int i = 0;
  if (deg >= 8) {
    int idx0 = csr[beg + 0], idx1 = csr[beg + 1], idx2 = csr[beg + 2], idx3 = csr[beg + 3];
    int idx4 = csr[beg + 4], idx5 = csr[beg + 5], idx6 = csr[beg + 6], idx7 = csr[beg + 7];
    for (; i + 16 <= deg; i += 8) {
      // prefetch next batch's indices (wave-uniform s_loads) before row gathers
      int n0 = csr[beg + i + 8],  n1 = csr[beg + i + 9];
      int n2 = csr[beg + i + 10], n3 = csr[beg + i + 11];
      int n4 = csr[beg + i + 12], n5 = csr[beg + i + 13];
      int n6 = csr[beg + i + 14], n7 = csr[beg + i + 15];
      ushort4 u0 = hv[(size_t)idx0 * 64], u1 = hv[(size_t)idx1 * 64];
      ushort4 u2 = hv[(size_t)idx2 * 64], u3 = hv[(size_t)idx3 * 64];
      ushort4 u4 = hv[(size_t)idx4 * 64], u5 = hv[(size_t)idx5 * 64];
      ushort4 u6 = hv[(size_t)idx6 * 64], u7 = hv[(size_t)idx7 * 64];
      a0 += b2f(u0.x) + b2f(u1.x) + b2f(u2.x) + b2f(u3.x)
          + b2f(u4.x) + b2f(u5.x) + b2f(u6.x) + b2f(u7.x);
      a1 += b2f(u0.y) + b2f(u1.y) + b2f(u2.y) + b2f(u3.y)
          + b2f(u4.y) + b2f(u5.y) + b2f(u6.y) + b2f(u7.y);
      a2 += b2f(u0.z) + b2f(u1.z) + b2f(u2.z) + b2f(u3.z)
          + b2f(u4.z) + b2f(u5.z) + b2f(u6.z) + b2f(u7.z);
      a3 += b2f(u0.w) + b2f(u1.w) + b2f(u2.w) + b2f(u3.w)
          + b2f(u4.w) + b2f(u5.w) + b2f(u6.w) + b2f(u7.w);
      idx0 = n0; idx1 = n1; idx2 = n2; idx3 = n3;
      idx4 = n4; idx5 = n5; idx6 = n6; idx7 = n7;
    }
    // drain the last prefetched batch
    {
      ushort4 u0 = hv[(size_t)idx0 * 64], u1 = hv[(size_t)idx1 * 64];
      ushort4 u2 = hv[(size_t)idx2 * 64], u3 = hv[(size_t)idx3 * 64];
      ushort4 u4 = hv[(size_t)idx4 * 64], u5 = hv[(size_t)idx5 * 64];
      ushort4 u6 = hv[(size_t)idx6 * 64], u7 = hv[(size_t)idx7 * 64];
      a0 += b2f(u0.x) + b2f(u1.x) + b2f(u2.x) + b2f(u3.x)
          + b2f(u4.x) + b2f(u5.x) + b2f(u6.x) + b2f(u7.x);
      a1 += b2f(u0.y) + b2f(u1.y) + b2f(u2.y) + b2f(u3.y)
          + b2f(u4.y) + b2f(u5.y) + b2f(u6.y) + b2f(u7.y);
      a2 += b2f(u0.z) + b2f(u1.z) + b2f(u2.z) + b2f(u3.z)
          + b2f(u4.z) + b2f(u5.z) + b2f(u6.z) + b2f(u7.z);
      a3 += b2f(u0.w) + b2f(u1.w) + b2f(u2.w) + b2f(u3.w)
          + b2f(u4.w) + b2f(u5.w) + b2f(u6.w) + b2f(u7.w);
      i += 8;
    }
  }
  for (; i + 4 <= deg; i += 4) {
    int s0 = csr[beg + i + 0], s1 = csr[beg + i + 1];
    int s2 = csr[beg + i + 2], s3 = csr[beg + i + 3];
    ushort4 u0 = hv[(size_t)s0 * 64], u1 = hv[(size_t)s1 * 64];
    ushort4 u2 = hv[(size_t)s2 * 64], u3 = hv[(size_t)s3 * 64];
    a0 += b2f(u0.x) + b2f(u1.x) + b2f(u2.x) + b2f(u3.x);
    a1 += b2f(u0.y) + b2f(u1.y) + b2f(u2.y) + b2f(u3.y);
    a2 += b2f(u0.z) + b2f(u1.z) + b2f(u2.z) + b2f(u3.z);
    a3 += b2f(u0.w) + b2f(u1.w) + b2f(u2.w) + b2f(u3.w);
  }
  for (; i < deg; ++i) {
    int s = csr[beg + i];
    ushort4 u = hv[(size_t)s * 64];
    a0 += b2f(u.x); a1 += b2f(u.y); a2 += b2f(u.z); a3 += b2f(u.w);
  }
  ushort4 o;
  o.x = f2b(a0); o.y = f2b(a1); o.z = f2b(a2); o.w = f2b(a3);
  *((ushort4*)out + (size_t)node * 64 + l) = o;
}

// ---------------- GEMM (proj only): C = relu(A @ W + bias) ----------------
__global__ __launch_bounds__(256) void k_gemm(const u16* __restrict__ A,
                                              const u16* __restrict__ BT,
                                              const float* __restrict__ bias,
                                              u16* __restrict__ C, int relu) {
  __shared__ __align__(16) u16 As[128 * LDSW];
  __shared__ __align__(16) u16 Bs[128 * LDSW];
  int tid = threadIdx.x;
  int bid = blockIdx.x;
  int tn = bid & 1, tm = bid >> 1;
  int w = tid >> 6, l = tid & 63;
  int wr = (w >> 1) * 64, wc = (w & 1) * 64;

  const u16* Ag = A + (size_t)tm * 128 * 256;
  const u16* Bg = BT + (size_t)tn * 128 * 256;

  f32x4 zz; zz[0] = 0.f; zz[1] = 0.f; zz[2] = 0.f; zz[3] = 0.f;
  f32x4 acc[4][4];
#pragma unroll
  for (int m = 0; m < 4; ++m)
#pragma unroll
    for (int n = 0; n < 4; ++n) acc[m][n] = zz;

  int r0 = w * 16 + (l >> 2);
  int r1 = r0 + 64;
  int kc = (l & 3) * 8;
  int w0 = r0 * LDSW + (l & 3) * 8;
  int w1 = r1 * LDSW + (l & 3) * 8;

  short8 pa0 = *(const short8*)(Ag + (size_t)r0 * 256 + kc);
  short8 pa1 = *(const short8*)(Ag + (size_t)r1 * 256 + kc);
  short8 pb0 = *(const short8*)(Bg + (size_t)r0 * 256 + kc);
  short8 pb1 = *(const short8*)(Bg + (size_t)r1 * 256 + kc);

  for (int kk = 0; kk < 8; ++kk) {
    *(short8*)&As[w0] = pa0;
    *(short8*)&As[w1] = pa1;
    *(short8*)&Bs[w0] = pb0;
    *(short8*)&Bs[w1] = pb1;
    if (kk < 7) {
      int k0 = (kk + 1) * 32 + kc;
      pa0 = *(const short8*)(Ag + (size_t)r0 * 256 + k0);
      pa1 = *(const short8*)(Ag + (size_t)r1 * 256 + k0);
      pb0 = *(const short8*)(Bg + (size_t)r0 * 256 + k0);
      pb1 = *(const short8*)(Bg + (size_t)r1 * 256 + k0);
    }
    __syncthreads();
    short8 af[4], bfr[4];
#pragma unroll
    for (int m = 0; m < 4; ++m) {
      int row = wr + m * 16 + (l & 15);
      af[m] = *(const short8*)&As[row * LDSW + (l >> 4) * 8];
    }
#pragma unroll
    for (int n = 0; n < 4; ++n) {
      int row = wc + n * 16 + (l & 15);
      bfr[n] = *(const short8*)&Bs[row * LDSW + (l >> 4) * 8];
    }
#pragma unroll
    for (int m = 0; m < 4; ++m)
#pragma unroll
      for (int n = 0; n < 4; ++n)
        acc[m][n] = __builtin_amdgcn_mfma_f32_16x16x32_bf16(af[m], bfr[n], acc[m][n], 0, 0, 0);
    __syncthreads();
  }

  int colb = tn * 128 + wc;
  int rowb = tm * 128 + wr + (l >> 4) * 4;
#pragma unroll
  for (int n = 0; n < 4; ++n) {
    int c = colb + n * 16 + (l & 15);
    float bz = bias[c];
#pragma unroll
    for (int m = 0; m < 4; ++m) {
      int r = rowb + m * 16;
#pragma unroll
      for (int i = 0; i < 4; ++i) {
        float v = acc[m][n][i] + bz;
        if (relu) v = fmaxf(v, 0.f);
        C[(size_t)(r + i) * 256 + c] = f2b(v);
      }
    }
  }
}

// ---------------- fused GIN MLP (64-row, R11 version): C = relu(A@W1+b1)@W2+b2 ----------------
__global__ __launch_bounds__(256) void k_mlp(const u16* __restrict__ A,
                                             const u16* __restrict__ B1T,
                                             const u16* __restrict__ B2T,
                                             const float* __restrict__ b1,
                                             const float* __restrict__ b2,
                                             u16* __restrict__ C,
                                             float* __restrict__ csum,
                                             float* __restrict__ csq) {
  __shared__ __align__(16) u16 As[64 * LDSW];
  __shared__ __align__(16) u16 Bs[256 * LDSW];
  __shared__ __align__(16) u16 C1[8 * 64 * LDSW];  // [chunk][row][k&31]
  int tid = threadIdx.x;
  int tm = blockIdx.x;
  int w = tid >> 6, l = tid & 63;
  int wc = w * 64;

  const u16* Ag = A + (size_t)tm * 64 * 256;

  int sr = tid >> 2;
  int skc = (tid & 3) * 8;
  int aw = sr * LDSW + skc;

  f32x4 zz; zz[0] = 0.f; zz[1] = 0.f; zz[2] = 0.f; zz[3] = 0.f;
  f32x4 acc[4][4];
#pragma unroll
  for (int m = 0; m < 4; ++m)
#pragma unroll
    for (int n = 0; n < 4; ++n) acc[m][n] = zz;

  // ---- phase 1: C1 = relu(A @ W1 + b1) ----
  short8 pa = *(const short8*)(Ag + (size_t)sr * 256 + skc);
  short8 pb[4];
#pragma unroll
  for (int j = 0; j < 4; ++j)
    pb[j] = *(const short8*)(B1T + (size_t)(sr + 64 * j) * 256 + skc);

  for (int kk = 0; kk < 8; ++kk) {
    *(short8*)&As[aw] = pa;
#pragma unroll
    for (int j = 0; j < 4; ++j)
      *(short8*)&Bs[(sr + 64 * j) * LDSW + skc] = pb[j];
    if (kk < 7) {
      int k0 = (kk + 1) * 32 + skc;
      pa = *(const short8*)(Ag + (size_t)sr * 256 + k0);
#pragma unroll
      for (int j = 0; j < 4; ++j)
        pb[j] = *(const short8*)(B1T + (size_t)(sr + 64 * j) * 256 + k0);
    }
    __syncthreads();
    short8 af[4], bfr[4];
#pragma unroll
    for (int m = 0; m < 4; ++m)
      af[m] = *(const short8*)&As[(m * 16 + (l & 15)) * LDSW + (l >> 4) * 8];
#pragma unroll
    for (int n = 0; n < 4; ++n)
      bfr[n] = *(const short8*)&Bs[(wc + n * 16 + (l & 15)) * LDSW + (l >> 4) * 8];
#pragma unroll
    for (int m = 0; m < 4; ++m)
#pragma unroll
      for (int n = 0; n < 4; ++n)
        acc[m][n] = __builtin_amdgcn_mfma_f32_16x16x32_bf16(af[m], bfr[n], acc[m][n], 0, 0, 0);
    __syncthreads();
  }

  // prefetch W2 chunk 0
  short8 qb[4];
#pragma unroll
  for (int j = 0; j < 4; ++j)
    qb[j] = *(const short8*)(B2T + (size_t)(sr + 64 * j) * 256 + skc);

  // epilogue 1 -> C1 (LDS, chunk-major), add b1, relu
  {
    int rbase = (l >> 4) * 4;
#pragma unroll
    for (int n = 0; n < 4; ++n) {
      int c = wc + n * 16 + (l & 15);
      float bz = b1[c];
      u16* c1p = &C1[(c >> 5) * (64 * LDSW) + (c & 31)];
#pragma unroll
      for (int m = 0; m < 4; ++m) {
#pragma unroll
        for (int i = 0; i < 4; ++i) {
          float v = fmaxf(acc[m][n][i] + bz, 0.f);
          c1p[(m * 16 + rbase + i) * LDSW] = f2b(v);
        }
        acc[m][n] = zz;
      }
    }
  }

  // ---- phase 2: C = C1 @ W2 + b2 ----
  for (int kk = 0; kk < 8; ++kk) {
#pragma unroll
    for (int j = 0; j < 4; ++j)
      *(short8*)&Bs[(sr + 64 * j) * LDSW + skc] = qb[j];
    if (kk < 7) {
      int k0 = (kk + 1) * 32 + skc;
#pragma unroll
      for (int j = 0; j < 4; ++j)
        qb[j] = *(const short8*)(B2T + (size_t)(sr + 64 * j) * 256 + k0);
    }
    __syncthreads();
    short8 af[4], bfr[4];
#pragma unroll
    for (int m = 0; m < 4; ++m)
      af[m] = *(const short8*)&C1[kk * (64 * LDSW) + (m * 16 + (l & 15)) * LDSW + (l >> 4) * 8];
#pragma unroll
    for (int n = 0; n < 4; ++n)
      bfr[n] = *(const short8*)&Bs[(wc + n * 16 + (l & 15)) * LDSW + (l >> 4) * 8];
#pragma unroll
    for (int m = 0; m < 4; ++m)
#pragma unroll
      for (int n = 0; n < 4; ++n)
        acc[m][n] = __builtin_amdgcn_mfma_f32_16x16x32_bf16(af[m], bfr[n], acc[m][n], 0, 0, 0);
    __syncthreads();
  }

  // epilogue 2 -> global + fused stats
  int rowb = tm * 64 + (l >> 4) * 4;
#pragma unroll
  for (int n = 0; n < 4; ++n) {
    int c = wc + n * 16 + (l & 15);
    float bz = b2[c];
    float s = 0.f, q = 0.f;
#pragma unroll
    for (int m = 0; m < 4; ++m) {
      int r = rowb + m * 16;
#pragma unroll
      for (int i = 0; i < 4; ++i) {
        float v = acc[m][n][i] + bz;
        C[(size_t)(r + i) * 256 + c] = f2b(v);
        if ((r + i) < NN) { s += v; q += v * v; }
      }
    }
    s += __shfl_xor(s, 16); s += __shfl_xor(s, 32);
    q += __shfl_xor(q, 16); q += __shfl_xor(q, 32);
    if ((l >> 4) == 0) {
      atomicAdd(&csum[c], s);
      atomicAdd(&csq[c], q);
    }
  }
}

// ---------------- head: embed + logits (fp32 out) ----------------
__global__ void k_head(const float* __restrict__ pooled, const int* __restrict__ gcnt,
                       const float* __restrict__ predW, const float* __restrict__ predb,
                       float* __restrict__ out) {
  __shared__ float pm[256];
  int g = blockIdx.x, t = threadIdx.x;
  float c = fmaxf((float)gcnt[g], 1.0f);
  float v = pooled[(size_t)g * 256 + t] / c;
  pm[t] = v;
  out[(size_t)g * 256 + t] = v;
  __syncthreads();
  if (t < NOTESD) {
    float acc = predb[t];
    for (int k = 0; k < 256; ++k)
      acc += pm[k] * predW[k * NOTESD + t];
    out[(size_t)GG * 256 + (size_t)g * NOTESD + t] = acc;
  }
}

extern "C" void kernel_launch(void* const* d_in, const int* in_sizes, int n_in,
                              void* d_out, int out_size, void* d_ws, size_t ws_size,
                              hipStream_t stream) {
  const float* x     = (const float*)d_in[0];
  const int*   ei    = (const int*)d_in[1];
  const int*   batch = (const int*)d_in[2];
  const float* fng   = (const float*)d_in[3];
  const float* fnb   = (const float*)d_in[4];
  const float* projW = (const float*)d_in[5];
  const float* projb = (const float*)d_in[6];
  const float* W1    = (const float*)d_in[7];
  const float* b1    = (const float*)d_in[8];
  const float* W2    = (const float*)d_in[9];
  const float* b2    = (const float*)d_in[10];
  const float* bng   = (const float*)d_in[11];
  const float* bnb   = (const float*)d_in[12];
  const float* predW = (const float*)d_in[13];
  const float* predb = (const float*)d_in[14];
  float* out = (float*)d_out;

  char* ws = (char*)d_ws;
  size_t off = 0;
  auto alloc = [&](size_t b) { size_t o = off; off += (b + 255) & ~(size_t)255; return o; };
  u16* h    = (u16*)(ws + alloc((size_t)MPAD * 256 * 2));
  u16* bufA = (u16*)(ws + alloc((size_t)MPAD * 256 * 2));
  u16* bufB = (u16*)(ws + alloc((size_t)MPAD * 256 * 2));
  u16* wt   = (u16*)(ws + alloc((size_t)9 * 65536 * 2));
  size_t statbytes = (size_t)(2560 + GG * 256) * 4 + GG * 4;
  float* statz = (float*)(ws + alloc(statbytes));
  int* cnt     = (int*)(ws + alloc((size_t)NN * 4));
  int* indptr  = (int*)(ws + alloc((size_t)NN * 4));
  int* cursor  = (int*)(ws + alloc((size_t)NN * 4));
  int* csum    = (int*)(ws + alloc(512));
  int* csr     = (int*)(ws + alloc((size_t)EE * 4));
  float* xsum = statz;
  float* xsq  = statz + 256;
  float* pooled = statz + 2560;
  int* gcnt = (int*)(statz + 2560 + GG * 256);

  const int* srcI = ei;
  const int* dstI = ei + EE;

  // zero stats+pooled+gcnt+cnt in one shot; zero bufA pad rows
  hipMemsetAsync(statz, 0, statbytes + (size_t)NN * 4, stream);
  hipMemsetAsync(bufA + (size_t)NN * 256, 0, (size_t)(MPAD - NN) * 256 * 2, stream);

  // CSR build
  k_hist<<<(EE + 255) / 256, 256, 0, stream>>>(dstI, cnt);
  k_scan1<<<NCHUNK, 512, 0, stream>>>(cnt, indptr, csum);
  k_scan3b<<<NCHUNK, 512, 0, stream>>>(csum, indptr, cursor);
  k_fill<<<(EE + 255) / 256, 256, 0, stream>>>(srcI, dstI, cursor, csr);

  // all weight transposes in one launch
  k_transpose_all<<<576, 256, 0, stream>>>(projW, W1, W2, wt);

  // feature BN -> bufA
  k_colstats_f32<<<512, 256, 0, stream>>>(x, xsum, xsq);
  k_bnx<<<512, 256, 0, stream>>>(x, xsum, xsq, fng, fnb, bufA);

  // projection: h = relu(xn @ projW + projb)
  k_gemm<<<TM_TILES * 2, 256, 0, stream>>>(bufA, wt, projb, h, 1);

  for (int l = 0; l < 4; ++l) {
    float* lsum = statz + 512 + l * 512;
    float* lsq  = lsum + 256;
    k_agg<<<(NN + 3) / 4, 256, 0, stream>>>(h, indptr, cnt, csr, bufA);
    k_mlp<<<MPAD / 64, 256, 0, stream>>>(bufA, wt + (size_t)(1 + l) * 65536,
                                         wt + (size_t)(5 + l) * 65536,
                                         b1 + (size_t)l * 256, b2 + (size_t)l * 256,
                                         bufB, lsum, lsq);
    if (l < 3) {
      k_bnres<<<512, 256, 0, stream>>>(bufB, lsum, lsq, bng + (size_t)l * 256,
                                       bnb + (size_t)l * 256, h);
    } else {
      k_bnres_pool<<<(NN + 127) / 128, 256, 0, stream>>>(bufB, lsum, lsq,
                                                         bng + (size_t)l * 256,
                                                         bnb + (size_t)l * 256, h,
                                                         batch, pooled, gcnt);
    }
  }

  // readout
  k_head<<<GG, 256, 0, stream>>>(pooled, gcnt, predW, predb, out);
}